// Round 1
// 410.200 us; speedup vs baseline: 1.1026x; 1.1026x over previous
//
#include <hip/hip_runtime.h>
#include <cmath>

#define BATCH 32
#define SEQLEN 512
#define NSAMP 1000
#define DMODEL 1024
#define NCHUNK 4

typedef __bf16 bf16x8_t __attribute__((ext_vector_type(8)));
typedef float f32x4_t __attribute__((ext_vector_type(4)));

__device__ __forceinline__ unsigned pack_bf2(float lo, float hi) {
    unsigned ulo = __float_as_uint(lo);
    unsigned uhi = __float_as_uint(hi);
    ulo = (ulo + 0x7fffu + ((ulo >> 16) & 1u)) >> 16;
    uhi = (uhi + 0x7fffu + ((uhi >> 16) & 1u)) & 0xffff0000u;
    return (ulo & 0xffffu) | uhi;
}

// TF log-uniform sampler expected-count, log-domain
__device__ __forceinline__ float log_expected_count(int id) {
    float idf = (float)id;
    float p = log1pf(1.0f / (idf + 1.0f)) * 0.09242316f; // 1/ln(50001)
    return logf(-expm1f(1000.0f * log1pf(-p)));
}

// async 16B global->LDS (dest = wave-uniform base + lane*16)
__device__ __forceinline__ void gl16(const void* g, void* l) {
    __builtin_amdgcn_global_load_lds(
        (const __attribute__((address_space(1))) unsigned int*)g,
        (__attribute__((address_space(3))) unsigned int*)l,
        16, 0, 0);
}

// ---- prep: W-row gather->bf16 (+adj), fp32 true-logit dot, and h->bf16 ----
// blocks [0, 8000): gather 4 rows of Wb each (32000 rows total)
// blocks [8000, 12096): true logits + hb store, 4 (b,t) rows each (16384 total)
__global__ __launch_bounds__(256) void prep_kernel(
    const float* __restrict__ h, const int* __restrict__ labels,
    const int* __restrict__ sids, const float* __restrict__ W,
    const float* __restrict__ bias, unsigned short* __restrict__ Wb,
    unsigned short* __restrict__ hb,
    float* __restrict__ adjw, float* __restrict__ tlw)
{
    const int w = threadIdx.x >> 6, lane = threadIdx.x & 63;
    if (blockIdx.x < 8000) {
        const int row = blockIdx.x * 4 + w;            // b*1000+s
        const int sv = sids[row];
        const float4* src = (const float4*)(W + (size_t)sv * DMODEL);
        unsigned short* dst = Wb + (size_t)row * DMODEL;
#pragma unroll
        for (int j = 0; j < 4; ++j) {
            float4 v = src[lane + j * 64];
            uint2 u;
            u.x = pack_bf2(v.x, v.y);
            u.y = pack_bf2(v.z, v.w);
            *(uint2*)(dst + (lane + j * 64) * 4) = u;
        }
        if (lane == 0) adjw[row] = bias[sv] - log_expected_count(sv);
    } else {
        const int r = (blockIdx.x - 8000) * 4 + w;     // b*512+t
        const int lab = labels[r];
        const float4* hp = (const float4*)(h + (size_t)r * DMODEL);
        const float4* wp = (const float4*)(W + (size_t)lab * DMODEL);
        unsigned short* hdst = hb + (size_t)r * DMODEL;
        float s = 0.0f;
#pragma unroll
        for (int j = 0; j < 4; ++j) {
            float4 a = hp[lane + j * 64];
            float4 c = wp[lane + j * 64];
            s += a.x * c.x + a.y * c.y + a.z * c.z + a.w * c.w;
            uint2 u;
            u.x = pack_bf2(a.x, a.y);
            u.y = pack_bf2(a.z, a.w);
            *(uint2*)(hdst + (lane + j * 64) * 4) = u;
        }
#pragma unroll
        for (int off = 32; off > 0; off >>= 1) s += __shfl_xor(s, off, 64);
        if (lane == 0) tlw[r] = s + bias[lab] - log_expected_count(lab);
    }
}

// ---- main: 64-t-row x 256-sample tile, BK=32, gload_lds dbuf, in-reg LSE ----
// grid (bb=32, chunk=4, tile_t=8): B-panel sharers differ by 128 in dispatch id,
// A-panel sharers by 32 -> same XCD (id%8) -> L2 locality.
__global__ __launch_bounds__(256, 3) void sampled_softmax_main(
    const int* __restrict__ labels, const int* __restrict__ sids,
    const unsigned short* __restrict__ hb, const unsigned short* __restrict__ Wb,
    const float* __restrict__ adjw,
    float* __restrict__ pm, float* __restrict__ pl)
{
    __shared__ __align__(16) unsigned short Ab[2][64 * 32];    //  8 KB
    __shared__ __align__(16) unsigned short Bb[2][256 * 32];   // 32 KB
    __shared__ int   sid_lds[256];
    __shared__ float adj_lds[256];
    __shared__ int   lab_lds[64];
    __shared__ float mpart[4][64];
    __shared__ float lpart[4][64];

    const int bb     = blockIdx.x;   // 0..31
    const int chunk  = blockIdx.y;   // 0..3
    const int tile_t = blockIdx.z;   // 0..7
    const int t0  = tile_t * 64;
    const int tid = threadIdx.x;
    const int w   = tid >> 6, l = tid & 63;
    const int lm  = l & 15,   q = l >> 4;
    const int rl4 = l >> 2,  cp = l & 3;

    {   // block-level index/adj staging
        const int s = chunk * 256 + tid;
        const bool v = s < NSAMP;
        sid_lds[tid] = v ? sids[bb * NSAMP + s] : -1;
        adj_lds[tid] = v ? adjw[bb * NSAMP + s] : 0.0f;
        if (tid < 64) lab_lds[tid] = labels[bb * SEQLEN + t0 + tid];
    }

    // staging: linear LDS dest, inverse-swizzled global source (rule #21)
    // swizzle s(r) = (r&3)^((r>>2)&3) -> 2-way (free) on frag ds_read_b128
    const int swzs = (rl4 & 3) ^ ((rl4 >> 2) & 3);
    const int cs = (cp ^ swzs) * 8;                    // element offset in 32-wide row
    const unsigned short* aS = hb + (size_t)(bb * SEQLEN + t0 + 16 * w + rl4) * DMODEL + cs;
    const unsigned short* bS[4];
#pragma unroll
    for (int j = 0; j < 4; ++j) {
        int rb = chunk * 256 + 64 * w + 16 * j + rl4;
        if (rb > NSAMP - 1) rb = NSAMP - 1;            // clamp (masked in LSE)
        bS[j] = Wb + (size_t)(bb * NSAMP + rb) * DMODEL + cs;
    }

    // fragment read offsets (swizzled)
    const int fswz = (lm & 3) ^ ((lm >> 2) & 3);
    const int fp = (q ^ fswz) * 8;
    int aoff[4], boff[4];
#pragma unroll
    for (int t = 0; t < 4; ++t) aoff[t] = (16 * t + lm) * 32 + fp;
#pragma unroll
    for (int c = 0; c < 4; ++c) boff[c] = (64 * w + 16 * c + lm) * 32 + fp;

    f32x4_t acc[4][4];
#pragma unroll
    for (int t = 0; t < 4; ++t)
#pragma unroll
        for (int c = 0; c < 4; ++c) acc[t][c] = (f32x4_t){0.f, 0.f, 0.f, 0.f};

    // prologue: stage kt=0 -> buf 0 (A: 1 instr/wave, B: 4 instr/wave)
    gl16(aS, &Ab[0][(16 * w) * 32]);
#pragma unroll
    for (int j = 0; j < 4; ++j) gl16(bS[j], &Bb[0][(64 * w + 16 * j) * 32]);
    __syncthreads();

    for (int kt = 0; kt < 32; ++kt) {
        const int cur = kt & 1;
        if (kt + 1 < 32) {   // issue next-tile loads FIRST (latency hides under MFMA)
            const int adv = (kt + 1) * 32;
            gl16(aS + adv, &Ab[cur ^ 1][(16 * w) * 32]);
#pragma unroll
            for (int j = 0; j < 4; ++j)
                gl16(bS[j] + adv, &Bb[cur ^ 1][(64 * w + 16 * j) * 32]);
        }
        const unsigned short* Ac = Ab[cur];
        const unsigned short* Bc = Bb[cur];
        bf16x8_t fa[4];
#pragma unroll
        for (int t = 0; t < 4; ++t) fa[t] = *(const bf16x8_t*)(Ac + aoff[t]);
#pragma unroll
        for (int c = 0; c < 4; ++c) {
            bf16x8_t fb = *(const bf16x8_t*)(Bc + boff[c]);
#pragma unroll
            for (int t = 0; t < 4; ++t)
                acc[t][c] = __builtin_amdgcn_mfma_f32_16x16x32_bf16(fa[t], fb, acc[t][c], 0, 0, 0);
        }
        __syncthreads();   // drains vmcnt (staging) + protects dbuf swap
    }

    // epilogue: in-register partial LSE.
    // C layout: row = 16*t + 4*q + i, col = 64*w + 16*c + lm
    float adjv[4]; int sidv[4]; bool cval[4];
#pragma unroll
    for (int c = 0; c < 4; ++c) {
        const int col = 64 * w + 16 * c + lm;
        adjv[c] = adj_lds[col];
        sidv[c] = sid_lds[col];
        cval[c] = (chunk * 256 + col) < NSAMP;
    }
#pragma unroll
    for (int t = 0; t < 4; ++t) {
#pragma unroll
        for (int i = 0; i < 4; ++i) {
            const int r = 16 * t + 4 * q + i;
            const int lab = lab_lds[r];
            float x[4]; bool ok[4];
            float m = -INFINITY;
#pragma unroll
            for (int c = 0; c < 4; ++c) {
                x[c] = acc[t][c][i] + adjv[c];
                ok[c] = cval[c] && (sidv[c] != lab);
                if (ok[c]) m = fmaxf(m, x[c]);
            }
            float ls = 0.0f;
#pragma unroll
            for (int c = 0; c < 4; ++c) ls += ok[c] ? __expf(x[c] - m) : 0.0f;
            // merge (m,l) across the 16 lanes holding this row's columns
#pragma unroll
            for (int off = 1; off < 16; off <<= 1) {
                const float mo = __shfl_xor(m, off, 64);
                const float lo = __shfl_xor(ls, off, 64);
                const float M  = fmaxf(m, mo);
                const float e1 = (ls > 0.0f) ? ls * __expf(m - M) : 0.0f;
                const float e2 = (lo > 0.0f) ? lo * __expf(mo - M) : 0.0f;
                m = M; ls = e1 + e2;
            }
            if (lm == 0) { mpart[w][r] = m; lpart[w][r] = ls; }
        }
    }
    __syncthreads();
    if (tid < 64) {
        float m = -INFINITY, lsum = 0.0f;
#pragma unroll
        for (int p = 0; p < 4; ++p) {
            const float mp = mpart[p][tid];
            const float lp = lpart[p][tid];
            if (lp > 0.0f) {
                if (mp > m) { lsum = lsum * __expf(m - mp) + lp; m = mp; }
                else        { lsum += lp * __expf(mp - m); }
            }
        }
        const int idx = (bb * SEQLEN + t0 + tid) * NCHUNK + chunk;
        pm[idx] = m;
        pl[idx] = lsum;
    }
}

// ---- combine: merge 4 partial (m,l) + true logit -> per-block loss sums ----
__global__ __launch_bounds__(256) void combine_kernel(
    const float* __restrict__ pm, const float* __restrict__ pl,
    const float* __restrict__ tlw, float* __restrict__ bsum)
{
    __shared__ float wsum[4];
    const int tid = threadIdx.x;
    const int w = tid >> 6, lane = tid & 63;
    const int idx = blockIdx.x * 256 + tid;      // 0..16383
    float m = -INFINITY, l = 0.0f;
#pragma unroll
    for (int c = 0; c < NCHUNK; ++c) {
        const float mp = pm[idx * NCHUNK + c];
        const float lp = pl[idx * NCHUNK + c];
        if (lp > 0.0f) {
            if (mp > m) { l = l * __expf(m - mp) + lp; m = mp; }
            else        { l += lp * __expf(mp - m); }
        }
    }
    const float t = tlw[idx];
    const float M = fmaxf(m, t);
    float loss = __logf(l * __expf(m - M) + __expf(t - M)) + M - t;
#pragma unroll
    for (int off = 32; off > 0; off >>= 1) loss += __shfl_xor(loss, off, 64);
    if (lane == 0) wsum[w] = loss;
    __syncthreads();
    if (tid == 0) bsum[blockIdx.x] = wsum[0] + wsum[1] + wsum[2] + wsum[3];
}

__global__ void finalize_kernel(const float* __restrict__ bsum, float* __restrict__ out) {
    float v = bsum[threadIdx.x];
#pragma unroll
    for (int off = 32; off > 0; off >>= 1) v += __shfl_xor(v, off, 64);
    if (threadIdx.x == 0) out[0] = v * (0.5f / (float)(BATCH * SEQLEN));
}

extern "C" void kernel_launch(void* const* d_in, const int* in_sizes, int n_in,
                              void* d_out, int out_size, void* d_ws, size_t ws_size,
                              hipStream_t stream) {
    const float* h      = (const float*)d_in[0];
    const int*   labels = (const int*)d_in[1];
    const int*   sids   = (const int*)d_in[2];
    const float* W      = (const float*)d_in[3];
    const float* bias   = (const float*)d_in[4];

    // workspace layout (~99.8 MB, 16B-aligned offsets)
    char* base = (char*)d_ws;
    unsigned short* Wb = (unsigned short*)base;                 // 65,536,000
    unsigned short* hb = (unsigned short*)(base + 65536000);    // 33,554,432
    float* adjw = (float*)(base + 99090432);                    //    128,000
    float* tlw  = (float*)(base + 99218432);                    //     65,536
    float* pmw  = (float*)(base + 99283968);                    //    262,144
    float* plw  = (float*)(base + 99546112);                    //    262,144
    float* bsum = (float*)(base + 99808256);                    //        256

    prep_kernel<<<dim3(12096), dim3(256), 0, stream>>>(h, labels, sids, W, bias, Wb, hb, adjw, tlw);
    sampled_softmax_main<<<dim3(32, NCHUNK, 8), dim3(256), 0, stream>>>(
        labels, sids, hb, Wb, adjw, pmw, plw);
    combine_kernel<<<dim3(64), dim3(256), 0, stream>>>(pmw, plw, tlw, bsum);
    finalize_kernel<<<dim3(1), dim3(64), 0, stream>>>(bsum, (float*)d_out);
}

// Round 2
// 407.665 us; speedup vs baseline: 1.1094x; 1.0062x over previous
//
#include <hip/hip_runtime.h>
#include <cmath>

#define BATCH 32
#define SEQLEN 512
#define NSAMP 1000
#define DMODEL 1024
#define NCHUNK 4

typedef __bf16 bf16x8_t __attribute__((ext_vector_type(8)));
typedef float f32x4_t __attribute__((ext_vector_type(4)));

__device__ __forceinline__ unsigned pack_bf2(float lo, float hi) {
    unsigned ulo = __float_as_uint(lo);
    unsigned uhi = __float_as_uint(hi);
    ulo = (ulo + 0x7fffu + ((ulo >> 16) & 1u)) >> 16;
    uhi = (uhi + 0x7fffu + ((uhi >> 16) & 1u)) & 0xffff0000u;
    return (ulo & 0xffffu) | uhi;
}

// TF log-uniform sampler expected-count, log-domain
__device__ __forceinline__ float log_expected_count(int id) {
    float idf = (float)id;
    float p = log1pf(1.0f / (idf + 1.0f)) * 0.09242316f; // 1/ln(50001)
    return logf(-expm1f(1000.0f * log1pf(-p)));
}

// async 16B global->LDS (dest = wave-uniform base + lane*16)
__device__ __forceinline__ void gl16(const void* g, void* l) {
    __builtin_amdgcn_global_load_lds(
        (const __attribute__((address_space(1))) unsigned int*)g,
        (__attribute__((address_space(3))) unsigned int*)l,
        16, 0, 0);
}

// ---- prep: W-row gather->bf16 (+adj), fp32 true-logit dot, and h->bf16 ----
__global__ __launch_bounds__(256) void prep_kernel(
    const float* __restrict__ h, const int* __restrict__ labels,
    const int* __restrict__ sids, const float* __restrict__ W,
    const float* __restrict__ bias, unsigned short* __restrict__ Wb,
    unsigned short* __restrict__ hb,
    float* __restrict__ adjw, float* __restrict__ tlw)
{
    const int w = threadIdx.x >> 6, lane = threadIdx.x & 63;
    if (blockIdx.x < 8000) {
        const int row = blockIdx.x * 4 + w;            // b*1000+s
        const int sv = sids[row];
        const float4* src = (const float4*)(W + (size_t)sv * DMODEL);
        unsigned short* dst = Wb + (size_t)row * DMODEL;
#pragma unroll
        for (int j = 0; j < 4; ++j) {
            float4 v = src[lane + j * 64];
            uint2 u;
            u.x = pack_bf2(v.x, v.y);
            u.y = pack_bf2(v.z, v.w);
            *(uint2*)(dst + (lane + j * 64) * 4) = u;
        }
        if (lane == 0) adjw[row] = bias[sv] - log_expected_count(sv);
    } else {
        const int r = (blockIdx.x - 8000) * 4 + w;     // b*512+t
        const int lab = labels[r];
        const float4* hp = (const float4*)(h + (size_t)r * DMODEL);
        const float4* wp = (const float4*)(W + (size_t)lab * DMODEL);
        unsigned short* hdst = hb + (size_t)r * DMODEL;
        float s = 0.0f;
#pragma unroll
        for (int j = 0; j < 4; ++j) {
            float4 a = hp[lane + j * 64];
            float4 c = wp[lane + j * 64];
            s += a.x * c.x + a.y * c.y + a.z * c.z + a.w * c.w;
            uint2 u;
            u.x = pack_bf2(a.x, a.y);
            u.y = pack_bf2(a.z, a.w);
            *(uint2*)(hdst + (lane + j * 64) * 4) = u;
        }
#pragma unroll
        for (int off = 32; off > 0; off >>= 1) s += __shfl_xor(s, off, 64);
        if (lane == 0) tlw[r] = s + bias[lab] - log_expected_count(lab);
    }
}

// ---- main: 64x256 tile, BK=32, 3-buffer depth-2 pipeline, counted vmcnt ----
// Per-kt: vmcnt(5) [tile kt landed, kt+1 in flight] -> raw s_barrier ->
// issue stage(kt+2) -> ds_read frags -> setprio(1) 16xMFMA setprio(0).
// Loads get ~2 iterations of latency cover; vmcnt never drains to 0 mid-loop.
__global__ __launch_bounds__(256, 2) void sampled_softmax_main(
    const int* __restrict__ labels, const int* __restrict__ sids,
    const unsigned short* __restrict__ hb, const unsigned short* __restrict__ Wb,
    const float* __restrict__ adjw,
    float* __restrict__ pm, float* __restrict__ pl)
{
    __shared__ __align__(16) unsigned short Ab[3][64 * 32];    // 12 KB
    __shared__ __align__(16) unsigned short Bb[3][256 * 32];   // 48 KB
    __shared__ int   sid_lds[256];
    __shared__ float adj_lds[256];
    __shared__ int   lab_lds[64];
    __shared__ float mpart[4][64];
    __shared__ float lpart[4][64];

    const int bb     = blockIdx.x;   // 0..31
    const int chunk  = blockIdx.y;   // 0..3
    const int tile_t = blockIdx.z;   // 0..7
    const int t0  = tile_t * 64;
    const int tid = threadIdx.x;
    const int w   = tid >> 6, l = tid & 63;
    const int lm  = l & 15,   q = l >> 4;
    const int rl4 = l >> 2,  cp = l & 3;

    {   // block-level index/adj staging (read only in epilogue)
        const int s = chunk * 256 + tid;
        const bool v = s < NSAMP;
        sid_lds[tid] = v ? sids[bb * NSAMP + s] : -1;
        adj_lds[tid] = v ? adjw[bb * NSAMP + s] : 0.0f;
        if (tid < 64) lab_lds[tid] = labels[bb * SEQLEN + t0 + tid];
    }

    // staging: linear LDS dest, inverse-swizzled global source (rule #21)
    // swizzle s(r) = (r&3)^((r>>2)&3) -> 2-way (free) on frag ds_read_b128
    const int swzs = (rl4 & 3) ^ ((rl4 >> 2) & 3);
    const int cs = (cp ^ swzs) * 8;                    // element offset in 32-wide row
    const unsigned short* aS = hb + (size_t)(bb * SEQLEN + t0 + 16 * w + rl4) * DMODEL + cs;
    const unsigned short* bS[4];
#pragma unroll
    for (int j = 0; j < 4; ++j) {
        int rb = chunk * 256 + 64 * w + 16 * j + rl4;
        if (rb > NSAMP - 1) rb = NSAMP - 1;            // clamp (masked in LSE)
        bS[j] = Wb + (size_t)(bb * NSAMP + rb) * DMODEL + cs;
    }

#define STAGE_TILE(KT, BUF)                                                   \
    do {                                                                      \
        const int _adv = (KT) * 32;                                           \
        gl16(aS + _adv, &Ab[BUF][(16 * w) * 32]);                             \
        gl16(bS[0] + _adv, &Bb[BUF][(64 * w) * 32]);                          \
        gl16(bS[1] + _adv, &Bb[BUF][(64 * w + 16) * 32]);                     \
        gl16(bS[2] + _adv, &Bb[BUF][(64 * w + 32) * 32]);                     \
        gl16(bS[3] + _adv, &Bb[BUF][(64 * w + 48) * 32]);                     \
    } while (0)

    // fragment read offsets (swizzled)
    const int fswz = (lm & 3) ^ ((lm >> 2) & 3);
    const int fp = (q ^ fswz) * 8;
    int aoff[4], boff[4];
#pragma unroll
    for (int t = 0; t < 4; ++t) aoff[t] = (16 * t + lm) * 32 + fp;
#pragma unroll
    for (int c = 0; c < 4; ++c) boff[c] = (64 * w + 16 * c + lm) * 32 + fp;

    f32x4_t acc[4][4];
#pragma unroll
    for (int t = 0; t < 4; ++t)
#pragma unroll
        for (int c = 0; c < 4; ++c) acc[t][c] = (f32x4_t){0.f, 0.f, 0.f, 0.f};

    // prologue: tiles 0 and 1 in flight (10 loads/wave), no vm drain.
    STAGE_TILE(0, 0);
    STAGE_TILE(1, 1);
    // make sid/adj/lab ds_writes visible; lgkmcnt does NOT touch vmcnt.
    asm volatile("s_waitcnt lgkmcnt(0)" ::: "memory");
    __builtin_amdgcn_s_barrier();

#pragma unroll
    for (int kt = 0; kt < 32; ++kt) {
        if (kt < 31) { asm volatile("s_waitcnt vmcnt(5)" ::: "memory"); }
        else         { asm volatile("s_waitcnt vmcnt(0)" ::: "memory"); }
        __builtin_amdgcn_s_barrier();
        // stage(kt+2): overwrites buf[(kt-1)%3]; all waves consumed it
        // (their ds_reads fed MFMAs before arriving at this barrier).
        if (kt + 2 < 32) STAGE_TILE(kt + 2, (kt + 2) % 3);

        const unsigned short* Ac = Ab[kt % 3];
        const unsigned short* Bc = Bb[kt % 3];
        bf16x8_t fa[4];
#pragma unroll
        for (int t = 0; t < 4; ++t) fa[t] = *(const bf16x8_t*)(Ac + aoff[t]);
        bf16x8_t fb[4];
#pragma unroll
        for (int c = 0; c < 4; ++c) fb[c] = *(const bf16x8_t*)(Bc + boff[c]);
        __builtin_amdgcn_s_setprio(1);
#pragma unroll
        for (int c = 0; c < 4; ++c)
#pragma unroll
            for (int t = 0; t < 4; ++t)
                acc[t][c] = __builtin_amdgcn_mfma_f32_16x16x32_bf16(fa[t], fb[c], acc[t][c], 0, 0, 0);
        __builtin_amdgcn_s_setprio(0);
    }
#undef STAGE_TILE

    // epilogue: in-register partial LSE.
    // C layout: row = 16*t + 4*q + i, col = 64*w + 16*c + lm
    float adjv[4]; int sidv[4]; bool cval[4];
#pragma unroll
    for (int c = 0; c < 4; ++c) {
        const int col = 64 * w + 16 * c + lm;
        adjv[c] = adj_lds[col];
        sidv[c] = sid_lds[col];
        cval[c] = (chunk * 256 + col) < NSAMP;
    }
#pragma unroll
    for (int t = 0; t < 4; ++t) {
#pragma unroll
        for (int i = 0; i < 4; ++i) {
            const int r = 16 * t + 4 * q + i;
            const int lab = lab_lds[r];
            float x[4]; bool ok[4];
            float m = -INFINITY;
#pragma unroll
            for (int c = 0; c < 4; ++c) {
                x[c] = acc[t][c][i] + adjv[c];
                ok[c] = cval[c] && (sidv[c] != lab);
                if (ok[c]) m = fmaxf(m, x[c]);
            }
            float ls = 0.0f;
#pragma unroll
            for (int c = 0; c < 4; ++c) ls += ok[c] ? __expf(x[c] - m) : 0.0f;
            // merge (m,l) across the 16 lanes holding this row's columns
#pragma unroll
            for (int off = 1; off < 16; off <<= 1) {
                const float mo = __shfl_xor(m, off, 64);
                const float lo = __shfl_xor(ls, off, 64);
                const float M  = fmaxf(m, mo);
                const float e1 = (ls > 0.0f) ? ls * __expf(m - M) : 0.0f;
                const float e2 = (lo > 0.0f) ? lo * __expf(mo - M) : 0.0f;
                m = M; ls = e1 + e2;
            }
            if (lm == 0) { mpart[w][r] = m; lpart[w][r] = ls; }
        }
    }
    __syncthreads();
    if (tid < 64) {
        float m = -INFINITY, lsum = 0.0f;
#pragma unroll
        for (int p = 0; p < 4; ++p) {
            const float mp = mpart[p][tid];
            const float lp = lpart[p][tid];
            if (lp > 0.0f) {
                if (mp > m) { lsum = lsum * __expf(m - mp) + lp; m = mp; }
                else        { lsum += lp * __expf(mp - m); }
            }
        }
        const int idx = (bb * SEQLEN + t0 + tid) * NCHUNK + chunk;
        pm[idx] = m;
        pl[idx] = lsum;
    }
}

// ---- combine: merge 4 partial (m,l) + true logit -> per-block loss sums ----
__global__ __launch_bounds__(256) void combine_kernel(
    const float* __restrict__ pm, const float* __restrict__ pl,
    const float* __restrict__ tlw, float* __restrict__ bsum)
{
    __shared__ float wsum[4];
    const int tid = threadIdx.x;
    const int w = tid >> 6, lane = tid & 63;
    const int idx = blockIdx.x * 256 + tid;      // 0..16383
    float m = -INFINITY, l = 0.0f;
#pragma unroll
    for (int c = 0; c < NCHUNK; ++c) {
        const float mp = pm[idx * NCHUNK + c];
        const float lp = pl[idx * NCHUNK + c];
        if (lp > 0.0f) {
            if (mp > m) { l = l * __expf(m - mp) + lp; m = mp; }
            else        { l += lp * __expf(mp - m); }
        }
    }
    const float t = tlw[idx];
    const float M = fmaxf(m, t);
    float loss = __logf(l * __expf(m - M) + __expf(t - M)) + M - t;
#pragma unroll
    for (int off = 32; off > 0; off >>= 1) loss += __shfl_xor(loss, off, 64);
    if (lane == 0) wsum[w] = loss;
    __syncthreads();
    if (tid == 0) bsum[blockIdx.x] = wsum[0] + wsum[1] + wsum[2] + wsum[3];
}

__global__ void finalize_kernel(const float* __restrict__ bsum, float* __restrict__ out) {
    float v = bsum[threadIdx.x];
#pragma unroll
    for (int off = 32; off > 0; off >>= 1) v += __shfl_xor(v, off, 64);
    if (threadIdx.x == 0) out[0] = v * (0.5f / (float)(BATCH * SEQLEN));
}

extern "C" void kernel_launch(void* const* d_in, const int* in_sizes, int n_in,
                              void* d_out, int out_size, void* d_ws, size_t ws_size,
                              hipStream_t stream) {
    const float* h      = (const float*)d_in[0];
    const int*   labels = (const int*)d_in[1];
    const int*   sids   = (const int*)d_in[2];
    const float* W      = (const float*)d_in[3];
    const float* bias   = (const float*)d_in[4];

    // workspace layout (~99.8 MB, 16B-aligned offsets)
    char* base = (char*)d_ws;
    unsigned short* Wb = (unsigned short*)base;                 // 65,536,000
    unsigned short* hb = (unsigned short*)(base + 65536000);    // 33,554,432
    float* adjw = (float*)(base + 99090432);                    //    128,000
    float* tlw  = (float*)(base + 99218432);                    //     65,536
    float* pmw  = (float*)(base + 99283968);                    //    262,144
    float* plw  = (float*)(base + 99546112);                    //    262,144
    float* bsum = (float*)(base + 99808256);                    //        256

    prep_kernel<<<dim3(12096), dim3(256), 0, stream>>>(h, labels, sids, W, bias, Wb, hb, adjw, tlw);
    sampled_softmax_main<<<dim3(32, NCHUNK, 8), dim3(256), 0, stream>>>(
        labels, sids, hb, Wb, adjw, pmw, plw);
    combine_kernel<<<dim3(64), dim3(256), 0, stream>>>(pmw, plw, tlw, bsum);
    finalize_kernel<<<dim3(1), dim3(64), 0, stream>>>(bsum, (float*)d_out);
}